// Round 9
// baseline (53.170 us; speedup 1.0000x reference)
//
#include <hip/hip_runtime.h>

#define BATCH 32
#define LATENT 128
#define NODE_DIM 8
#define MAX_NODES 512
#define H_NODE 128
#define H_EDGE 64

typedef _Float16 h2 __attribute__((ext_vector_type(2)));

static __device__ __forceinline__ h2 u32_to_h2(unsigned int x) {
    union { unsigned int u; h2 h; } c; c.u = x; return c.h;
}
static __device__ __forceinline__ unsigned int h2_to_u32(h2 x) {
    union { unsigned int u; h2 h; } c; c.h = x; return c.u;
}

#if __has_builtin(__builtin_amdgcn_fdot2)
#define FDOT2(a, b, c) __builtin_amdgcn_fdot2((a), (b), (c), false)
#else
#define FDOT2(a, b, c) ((c) + (float)(a).x * (float)(b).x + (float)(a).y * (float)(b).y)
#endif

// ws layout: UPKH u32[32][32][512] (2MB) | VH u32[32][512][32] (2MB) | E2H u32[32]
#define UPKH_DWORDS (BATCH * 32 * MAX_NODES)
#define VH_DWORDS   (BATCH * MAX_NODES * 32)

// 72 (bi,jt) tiles per batch, bi-grouped, packed (bi<<4)|jt.
// bi=0: jt 0..15 | bi=1: 2..15 | bi=2: 4..15 | ... | bi=7: 14..15
__device__ const unsigned char TILE_CODE[72] = {
    0x00,0x01,0x02,0x03,0x04,0x05,0x06,0x07,0x08,0x09,0x0A,0x0B,0x0C,0x0D,0x0E,0x0F,
    0x12,0x13,0x14,0x15,0x16,0x17,0x18,0x19,0x1A,0x1B,0x1C,0x1D,0x1E,0x1F,
    0x24,0x25,0x26,0x27,0x28,0x29,0x2A,0x2B,0x2C,0x2D,0x2E,0x2F,
    0x36,0x37,0x38,0x39,0x3A,0x3B,0x3C,0x3D,0x3E,0x3F,
    0x48,0x49,0x4A,0x4B,0x4C,0x4D,0x4E,0x4F,
    0x5A,0x5B,0x5C,0x5D,0x5E,0x5F,
    0x6C,0x6D,0x6E,0x6F,
    0x7E,0x7F
};

// ---------------------------------------------------------------------------
// Kernel 1: nodes (f32, d_out) + U/V precompute in packed f16 + E2 packing.
// ---------------------------------------------------------------------------
__global__ __launch_bounds__(256) void gen_nodes_uv(
    const float* __restrict__ z,  const float* __restrict__ W1,
    const float* __restrict__ b1, const float* __restrict__ W2,
    const float* __restrict__ b2, const float* __restrict__ E1,
    const float* __restrict__ eb1, const float* __restrict__ E2,
    float* __restrict__ nodes_out, unsigned int* __restrict__ UPKH,
    unsigned int* __restrict__ VH, unsigned int* __restrict__ E2H)
{
    const int b      = blockIdx.x;
    const int mslice = blockIdx.y;     // 0..15, 256 cols each
    const int tid    = threadIdx.x;    // 0..255
    const int i0     = mslice * 32;    // first node owned by this block

    __shared__ float sz[LATENT];
    __shared__ float sh[H_NODE];
    __shared__ float sE1[2 * NODE_DIM][H_EDGE];
    __shared__ float sEb1[H_EDGE];
    __shared__ float sN[32][NODE_DIM];

    if (tid < LATENT) sz[tid] = z[b * LATENT + tid];
    for (int idx = tid; idx < 2 * NODE_DIM * H_EDGE; idx += 256)
        (&sE1[0][0])[idx] = E1[idx];
    if (tid < H_EDGE) sEb1[tid] = eb1[tid];

    // E2 -> packed f16x2 in ws (once, by block (0,0))
    if (b == 0 && mslice == 0 && tid < 32) {
        h2 w = { (_Float16)E2[2 * tid], (_Float16)E2[2 * tid + 1] };
        E2H[tid] = h2_to_u32(w);
    }
    __syncthreads();

    if (tid < H_NODE) {
        float acc = b1[tid];
#pragma unroll 8
        for (int k = 0; k < LATENT; ++k)
            acc += sz[k] * W1[k * H_NODE + tid];
        sh[tid] = fmaxf(acc, 0.0f);
    }
    __syncthreads();

    const int m = mslice * 256 + tid;
    float acc = b2[m];
#pragma unroll 8
    for (int k = 0; k < H_NODE; ++k)
        acc += sh[k] * W2[(size_t)k * (MAX_NODES * NODE_DIM) + m];
    nodes_out[(size_t)b * (MAX_NODES * NODE_DIM) + m] = acc;
    sN[tid >> 3][tid & 7] = acc;
    __syncthreads();

    {   // U' -> f16x2, layout [b][c2][i]
        const int il = tid & 31;
        const int cg = tid >> 5;
#pragma unroll
        for (int rep = 0; rep < 4; ++rep) {
            const int c2 = rep * 8 + cg;
            const int c  = 2 * c2;
            float ua = sEb1[c], ub = sEb1[c + 1];
#pragma unroll
            for (int d = 0; d < NODE_DIM; ++d) {
                const float nd = sN[il][d];
                ua += nd * sE1[d][c];
                ub += nd * sE1[d][c + 1];
            }
            h2 uu = { (_Float16)ua, (_Float16)ub };
            UPKH[((size_t)b * 32 + c2) * MAX_NODES + i0 + il] = h2_to_u32(uu);
        }
    }
    {   // V' -> f16x2, layout [b][j][c2] (128B rows)
        const int jl = tid >> 3;
        const int cq = tid & 7;
#pragma unroll
        for (int rep = 0; rep < 4; ++rep) {
            const int c2 = rep * 8 + cq;
            const int c  = 2 * c2;
            float va = 0.f, vb = 0.f;
#pragma unroll
            for (int d = 0; d < NODE_DIM; ++d) {
                const float nd = sN[jl][d];
                va += nd * sE1[NODE_DIM + d][c];
                vb += nd * sE1[NODE_DIM + d][c + 1];
            }
            h2 vv = { (_Float16)va, (_Float16)vb };
            VH[((size_t)(b * MAX_NODES + i0 + jl) << 5) + c2] = h2_to_u32(vv);
        }
    }
}

// ---------------------------------------------------------------------------
// Kernel 2: edge probabilities + adjacency. Persistent balanced blocks:
// grid (24, 32); block owns exactly 3 consecutive tiles of the bi-grouped
// TILE_CODE list -> U registers reused across tiles (reload only on bi
// change), E2 read pre-packed (4 uniform 16B loads), V rows via uniform
// scalar-path loads (L2-hot). Inner math: pk_add/pk_max/fdot2 (f16).
// ---------------------------------------------------------------------------
__global__ __launch_bounds__(256) void edge_gen(
    const unsigned int* __restrict__ UPKH, const unsigned int* __restrict__ VH,
    const unsigned int* __restrict__ E2H, const float* __restrict__ eb2,
    float* __restrict__ adj)
{
    const int b   = blockIdx.y;
    const int blk = blockIdx.x;              // 0..23, owns tiles 3*blk..3*blk+2
    const int tid  = threadIdx.x;
    const int lane = tid & 63;
    const int wv   = tid >> 6;               // 0..3

    __shared__ float P[32][65];              // mirror staging only (8.3 KB)

    // E2 packed f16x2: 32 dwords, uniform loads
    unsigned int wb[32];
#pragma unroll
    for (int c2 = 0; c2 < 32; ++c2) wb[c2] = E2H[c2];

    const float bias = eb2[0];
    float* adjb = adj + (size_t)b * MAX_NODES * MAX_NODES;
    const h2 zh = { (_Float16)0.f, (_Float16)0.f };

    unsigned int uA[32];
    int cur_bi = -1;

#pragma unroll 1
    for (int it = 0; it < 3; ++it) {
        const int code = TILE_CODE[3 * blk + it];
        const int bi = code >> 4, jt = code & 15;
        const bool partial = (jt >> 1) == bi;
        const int i0 = bi * 64, j0 = jt * 32;
        const int i  = i0 + lane;

        if (bi != cur_bi) {                  // uniform branch; ~1 reload/block
            cur_bi = bi;
#pragma unroll
            for (int c2 = 0; c2 < 32; ++c2)
                uA[c2] = UPKH[((size_t)b * 32 + c2) * MAX_NODES + i];
        }

#pragma unroll 2
        for (int jj = 0; jj < 8; ++jj) {
            const int jl = wv * 8 + jj;      // 0..31
            const int j  = j0 + jl;
            // wave-uniform V-row pointer -> SGPR base, scalar-path loads
            const int jfl = __builtin_amdgcn_readfirstlane(j);
            const uint4* vrow = (const uint4*)(VH + ((size_t)(b * MAX_NODES + jfl) << 5));

            float a0 = 0.f, a1 = 0.f;
#pragma unroll
            for (int q = 0; q < 8; ++q) {
                const uint4 vv = vrow[q];    // 16B uniform load
#pragma unroll
                for (int k = 0; k < 4; ++k) {
                    const int c2 = 4 * q + k;
                    unsigned int vu = (k == 0) ? vv.x : (k == 1) ? vv.y
                                    : (k == 2) ? vv.z : vv.w;
                    const h2 v = u32_to_h2(vu);
                    const h2 w = u32_to_h2(wb[c2]);
                    h2 s = u32_to_h2(uA[c2]) + v;
                    s = __builtin_elementwise_max(s, zh);
                    if (k & 1) a1 = FDOT2(s, w, a1);
                    else       a0 = FDOT2(s, w, a0);
                }
            }
            const float x = a0 + a1 + bias;
            const float p = __builtin_amdgcn_rcpf(1.0f + __expf(-x));

            if (!partial) {
                adjb[(size_t)j * MAX_NODES + i] = p;     // lower half, coalesced
                P[jl][lane] = p;                         // stage for mirror
            } else {
                if (i < j)       { adjb[(size_t)j * MAX_NODES + i] = p;
                                   adjb[(size_t)i * MAX_NODES + j] = p; }
                else if (i == j)   adjb[(size_t)j * MAX_NODES + i] = 0.0f;
            }
        }

        if (!partial) {                      // uniform per block-iteration
            __syncthreads();
            // mirror: adj[i0+r][j0..j0+31]; thread owns row r = tid&63, quarter q
            const int r = tid & 63;
            const int q = tid >> 6;          // 0..3
            const size_t rowbase = (size_t)(i0 + r) * MAX_NODES + j0 + q * 8;
            float4 o0, o1;
            o0.x = P[q * 8 + 0][r]; o0.y = P[q * 8 + 1][r];
            o0.z = P[q * 8 + 2][r]; o0.w = P[q * 8 + 3][r];
            o1.x = P[q * 8 + 4][r]; o1.y = P[q * 8 + 5][r];
            o1.z = P[q * 8 + 6][r]; o1.w = P[q * 8 + 7][r];
            *(float4*)&adjb[rowbase]     = o0;
            *(float4*)&adjb[rowbase + 4] = o1;
            __syncthreads();                 // P safe to overwrite next tile
        }
    }
}

// ---------------------------------------------------------------------------
extern "C" void kernel_launch(void* const* d_in, const int* in_sizes, int n_in,
                              void* d_out, int out_size, void* d_ws, size_t ws_size,
                              hipStream_t stream)
{
    const float* z   = (const float*)d_in[0];
    const float* W1  = (const float*)d_in[1];
    const float* b1  = (const float*)d_in[2];
    const float* W2  = (const float*)d_in[3];
    const float* b2  = (const float*)d_in[4];
    const float* E1  = (const float*)d_in[5];
    const float* eb1 = (const float*)d_in[6];
    const float* E2  = (const float*)d_in[7];
    const float* eb2 = (const float*)d_in[8];

    float* nodes_out = (float*)d_out;                                   // [32,512,8]
    float* adj       = (float*)d_out + BATCH * MAX_NODES * NODE_DIM;    // [32,512,512]

    unsigned int* UPKH = (unsigned int*)d_ws;       // 2 MB
    unsigned int* VHp  = UPKH + UPKH_DWORDS;        // 2 MB
    unsigned int* E2H  = VHp + VH_DWORDS;           // 128 B

    dim3 g1(BATCH, 16);
    gen_nodes_uv<<<g1, 256, 0, stream>>>(z, W1, b1, W2, b2, E1, eb1, E2,
                                         nodes_out, UPKH, VHp, E2H);

    dim3 g2(24, BATCH);
    edge_gen<<<g2, 256, 0, stream>>>(UPKH, VHp, E2H, eb2, adj);
}

// Round 10
// 46.286 us; speedup vs baseline: 1.1487x; 1.1487x over previous
//
#include <hip/hip_runtime.h>

#define BATCH 32
#define LATENT 128
#define NODE_DIM 8
#define MAX_NODES 512
#define H_NODE 128
#define H_EDGE 64

typedef _Float16 h2 __attribute__((ext_vector_type(2)));

static __device__ __forceinline__ h2 u32_to_h2(unsigned int x) {
    union { unsigned int u; h2 h; } c; c.u = x; return c.h;
}
static __device__ __forceinline__ unsigned int h2_to_u32(h2 x) {
    union { unsigned int u; h2 h; } c; c.h = x; return c.u;
}

#if __has_builtin(__builtin_amdgcn_fdot2)
#define FDOT2(a, b, c) __builtin_amdgcn_fdot2((a), (b), (c), false)
#else
#define FDOT2(a, b, c) ((c) + (float)(a).x * (float)(b).x + (float)(a).y * (float)(b).y)
#endif

// ws layout: UPKH u32[32][32][512] (2MB) | VH u32[32][512][32] (2MB)
//            | E2H u32[32] | Hws f32[32][128]
#define UPKH_DWORDS (BATCH * 32 * MAX_NODES)
#define VH_DWORDS   (BATCH * MAX_NODES * 32)

// ---------------------------------------------------------------------------
// Kernel 0: h = relu(z@W1+b1) per batch -> ws (512 B/batch). 32 blocks.
// ---------------------------------------------------------------------------
__global__ __launch_bounds__(128) void h_gen(
    const float* __restrict__ z, const float* __restrict__ W1,
    const float* __restrict__ b1, float* __restrict__ Hws)
{
    const int b = blockIdx.x, tid = threadIdx.x;
    __shared__ float sz[LATENT];
    sz[tid] = z[b * LATENT + tid];
    __syncthreads();
    float acc = b1[tid];
#pragma unroll 8
    for (int k = 0; k < LATENT; ++k)
        acc += sz[k] * W1[k * H_NODE + tid];
    Hws[b * H_NODE + tid] = fmaxf(acc, 0.0f);
}

// ---------------------------------------------------------------------------
// Kernel 1: nodes (f32, d_out) + U/V precompute in packed f16 + E2 packing.
// h read from ws (L2-hot) -- no redundant recompute, no W1 re-read.
// ---------------------------------------------------------------------------
__global__ __launch_bounds__(256) void gen_nodes_uv(
    const float* __restrict__ Hws, const float* __restrict__ W2,
    const float* __restrict__ b2,  const float* __restrict__ E1,
    const float* __restrict__ eb1, const float* __restrict__ E2,
    float* __restrict__ nodes_out, unsigned int* __restrict__ UPKH,
    unsigned int* __restrict__ VH, unsigned int* __restrict__ E2H)
{
    const int b      = blockIdx.x;
    const int mslice = blockIdx.y;     // 0..15, 256 cols each
    const int tid    = threadIdx.x;    // 0..255
    const int i0     = mslice * 32;    // first node owned by this block

    __shared__ float sh[H_NODE];
    __shared__ float sE1[2 * NODE_DIM][H_EDGE];
    __shared__ float sEb1[H_EDGE];
    __shared__ float sN[32][NODE_DIM];

    if (tid < H_NODE) sh[tid] = Hws[b * H_NODE + tid];
    for (int idx = tid; idx < 2 * NODE_DIM * H_EDGE; idx += 256)
        (&sE1[0][0])[idx] = E1[idx];
    if (tid < H_EDGE) sEb1[tid] = eb1[tid];

    // E2 -> packed f16x2 in ws (once, by block (0,0))
    if (b == 0 && mslice == 0 && tid < 32) {
        h2 w = { (_Float16)E2[2 * tid], (_Float16)E2[2 * tid + 1] };
        E2H[tid] = h2_to_u32(w);
    }
    __syncthreads();

    const int m = mslice * 256 + tid;
    float acc = b2[m];
#pragma unroll 8
    for (int k = 0; k < H_NODE; ++k)
        acc += sh[k] * W2[(size_t)k * (MAX_NODES * NODE_DIM) + m];
    nodes_out[(size_t)b * (MAX_NODES * NODE_DIM) + m] = acc;
    sN[tid >> 3][tid & 7] = acc;
    __syncthreads();

    {   // U' -> f16x2, layout [b][c2][i]
        const int il = tid & 31;
        const int cg = tid >> 5;
#pragma unroll
        for (int rep = 0; rep < 4; ++rep) {
            const int c2 = rep * 8 + cg;
            const int c  = 2 * c2;
            float ua = sEb1[c], ub = sEb1[c + 1];
#pragma unroll
            for (int d = 0; d < NODE_DIM; ++d) {
                const float nd = sN[il][d];
                ua += nd * sE1[d][c];
                ub += nd * sE1[d][c + 1];
            }
            h2 uu = { (_Float16)ua, (_Float16)ub };
            UPKH[((size_t)b * 32 + c2) * MAX_NODES + i0 + il] = h2_to_u32(uu);
        }
    }
    {   // V' -> f16x2, layout [b][j][c2] (128B rows)
        const int jl = tid >> 3;
        const int cq = tid & 7;
#pragma unroll
        for (int rep = 0; rep < 4; ++rep) {
            const int c2 = rep * 8 + cq;
            const int c  = 2 * c2;
            float va = 0.f, vb = 0.f;
#pragma unroll
            for (int d = 0; d < NODE_DIM; ++d) {
                const float nd = sN[jl][d];
                va += nd * sE1[NODE_DIM + d][c];
                vb += nd * sE1[NODE_DIM + d][c + 1];
            }
            h2 vv = { (_Float16)va, (_Float16)vb };
            VH[((size_t)(b * MAX_NODES + i0 + jl) << 5) + c2] = h2_to_u32(vv);
        }
    }
}

// ---------------------------------------------------------------------------
// Kernel 2: edge probabilities + adjacency. R7 body (best measured):
// tile 64 i x 32 j, 4 waves; lane owns i, wave owns 8 j; V tile in LDS read
// b128 broadcast; uA in VGPRs. Changes vs R7: launch_bounds(256,4) (VGPR cap
// 128 -> no forced spill) and E2 pre-packed (32 uniform dword loads).
// 72 tiles/batch (jt >= 2*bi); partial iff (jt>>1)==bi.
// ---------------------------------------------------------------------------
__global__ __launch_bounds__(256, 4) void edge_gen(
    const unsigned int* __restrict__ UPKH, const unsigned int* __restrict__ VH,
    const unsigned int* __restrict__ E2H, const float* __restrict__ eb2,
    float* __restrict__ adj)
{
    const int b = blockIdx.y;
    // decode tile: bi in 0..7 (64-wide i), jt in 2*bi..15 (32-wide j)
    int t = blockIdx.x, bi = 0;
    while (t >= 16 - 2 * bi) { t -= 16 - 2 * bi; ++bi; }
    const int jt = 2 * bi + t;
    const bool partial = (jt >> 1) == bi;    // j-window inside i-block

    const int tid  = threadIdx.x;
    const int lane = tid & 63;
    const int wv   = tid >> 6;               // 0..3
    const int i0 = bi * 64, j0 = jt * 32;
    const int i  = i0 + lane;

    __shared__ unsigned int sV[32 * 32];     // 32 rows x 64ch f16 = 4 KB
    __shared__ float P[32][65];              // tile probs for mirror (8.3 KB)

    // stage V tile: 4 KB contiguous, 1 float4 per thread
    {
        const float4* src = (const float4*)(VH + ((size_t)(b * MAX_NODES + j0) << 5));
        ((float4*)sV)[tid] = src[tid];
    }

    // U row for this lane: 32 f16x2 dwords, coalesced per c2
    unsigned int uA[32];
#pragma unroll
    for (int c2 = 0; c2 < 32; ++c2)
        uA[c2] = UPKH[((size_t)b * 32 + c2) * MAX_NODES + i];

    // E2 packed f16x2: 32 uniform dword loads (SGPR path)
    unsigned int wb[32];
#pragma unroll
    for (int c2 = 0; c2 < 32; ++c2) wb[c2] = E2H[c2];

    const float bias = eb2[0];
    float* adjb = adj + (size_t)b * MAX_NODES * MAX_NODES;
    const h2 zh = { (_Float16)0.f, (_Float16)0.f };
    __syncthreads();

#pragma unroll 1
    for (int jj = 0; jj < 8; ++jj) {
        const int jl = wv * 8 + jj;          // 0..31
        const int j  = j0 + jl;
        const float4* vrow = (const float4*)&sV[jl * 32];

        float a0 = 0.f, a1 = 0.f;
#pragma unroll
        for (int q = 0; q < 8; ++q) {
            union { float4 f4; unsigned int u[4]; } vv;
            vv.f4 = vrow[q];                 // ds_read_b128, uniform
#pragma unroll
            for (int k = 0; k < 4; ++k) {
                const int c2 = 4 * q + k;
                const h2 v = u32_to_h2(vv.u[k]);
                const h2 w = u32_to_h2(wb[c2]);
                h2 s = u32_to_h2(uA[c2]) + v;
                s = __builtin_elementwise_max(s, zh);
                if (k & 1) a1 = FDOT2(s, w, a1);
                else       a0 = FDOT2(s, w, a0);
            }
        }
        const float x = a0 + a1 + bias;
        const float p = __builtin_amdgcn_rcpf(1.0f + __expf(-x));

        if (!partial) {
            adjb[(size_t)j * MAX_NODES + i] = p;     // lower half, coalesced
            P[jl][lane] = p;                         // stage for mirror
        } else {
            if (i < j)       { adjb[(size_t)j * MAX_NODES + i] = p;
                               adjb[(size_t)i * MAX_NODES + j] = p; }
            else if (i == j)   adjb[(size_t)j * MAX_NODES + i] = 0.0f;
        }
    }

    if (!partial) {
        __syncthreads();
        // mirror: adj[i0+r][j0..j0+31]; thread owns row r = tid&63, quarter q
        const int r = tid & 63;
        const int q = tid >> 6;              // 0..3
        const size_t rowbase = (size_t)(i0 + r) * MAX_NODES + j0 + q * 8;
        float4 o0, o1;
        o0.x = P[q * 8 + 0][r]; o0.y = P[q * 8 + 1][r];
        o0.z = P[q * 8 + 2][r]; o0.w = P[q * 8 + 3][r];
        o1.x = P[q * 8 + 4][r]; o1.y = P[q * 8 + 5][r];
        o1.z = P[q * 8 + 6][r]; o1.w = P[q * 8 + 7][r];
        *(float4*)&adjb[rowbase]     = o0;
        *(float4*)&adjb[rowbase + 4] = o1;
    }
}

// ---------------------------------------------------------------------------
extern "C" void kernel_launch(void* const* d_in, const int* in_sizes, int n_in,
                              void* d_out, int out_size, void* d_ws, size_t ws_size,
                              hipStream_t stream)
{
    const float* z   = (const float*)d_in[0];
    const float* W1  = (const float*)d_in[1];
    const float* b1  = (const float*)d_in[2];
    const float* W2  = (const float*)d_in[3];
    const float* b2  = (const float*)d_in[4];
    const float* E1  = (const float*)d_in[5];
    const float* eb1 = (const float*)d_in[6];
    const float* E2  = (const float*)d_in[7];
    const float* eb2 = (const float*)d_in[8];

    float* nodes_out = (float*)d_out;                                   // [32,512,8]
    float* adj       = (float*)d_out + BATCH * MAX_NODES * NODE_DIM;    // [32,512,512]

    unsigned int* UPKH = (unsigned int*)d_ws;       // 2 MB
    unsigned int* VHp  = UPKH + UPKH_DWORDS;        // 2 MB
    unsigned int* E2H  = VHp + VH_DWORDS;           // 128 B
    float*        Hws  = (float*)(E2H + 32);        // 16 KB

    h_gen<<<BATCH, 128, 0, stream>>>(z, W1, b1, Hws);

    dim3 g1(BATCH, 16);
    gen_nodes_uv<<<g1, 256, 0, stream>>>(Hws, W2, b2, E1, eb1, E2,
                                         nodes_out, UPKH, VHp, E2H);

    dim3 g2(72, BATCH);
    edge_gen<<<g2, 256, 0, stream>>>(UPKH, VHp, E2H, eb2, adj);
}